// Round 17
// baseline (249.734 us; speedup 1.0000x reference)
//
#include <hip/hip_runtime.h>

#define NNODES 100000
#define NEDGES 3200000
#define NBKT 196        // buckets of 512 nodes (dst>>9)
#define NTILES2 1563    // bin tiles of 2048 edges
#define NGB 1563        // ceil(NNODES/64) GEMM blocks (64 rows)
#define BSTRIDE 18432   // fixed pairbuf/ebuf stride per bucket (mean 16327 + 16 sigma)
#define GCPAD 16        // gcur stride in words: one 64B cache line per bucket

typedef unsigned int uint;
typedef unsigned short ushort;
typedef unsigned char uchar;
typedef __attribute__((ext_vector_type(8))) short short8;   // 8 bf16 (4 VGPRs)
typedef __attribute__((ext_vector_type(4))) float f32x4;
typedef __attribute__((ext_vector_type(2))) float f32x2;

__device__ inline ushort bf16_rne(float f) {
    uint u = __float_as_uint(f);
    return (ushort)((u + 0x7FFFu + ((u >> 16) & 1u)) >> 16);
}
__device__ inline uint pack_bf2(float a, float b) {
    return (uint)bf16_rne(a) | ((uint)bf16_rne(b) << 16);
}
__device__ inline float2 unpack_bf2(uint v) {
    float2 r;
    r.x = __uint_as_float(v << 16);
    r.y = __uint_as_float(v & 0xFFFF0000u);
    return r;
}

// ---- fp8 e4m3fn (OCP) encode/decode; encoder flushes |v|<2^-6 to 0 ----
__device__ inline uchar f32_to_fp8(float f) {
    uint u = __float_as_uint(f);
    uint s = (u >> 24) & 0x80u;
    uint e = (u >> 23) & 0xFFu;
    if (e < 121u) return (uchar)s;  // flush to signed zero
    uint m = u & 0x7FFFFFu;
    uint r = (m + 0x7FFFFu + ((m >> 20) & 1u)) >> 20;  // RNE to 3 bits
    uint em = ((e - 120u) << 3) + r;                   // carry folds into exp
    return (uchar)(s | em);
}
__device__ inline float fp8_dec(uint b) {
    uint s = (b & 0x80u) << 24;
    uint em = b & 0x7Fu;
    float v = __uint_as_float(s | ((em + 960u) << 20));
    return em ? v : 0.0f;
}
__device__ inline float2 fp8_lo2(uint pk) {
#if __has_builtin(__builtin_amdgcn_cvt_pk_f32_fp8)
    f32x2 r = __builtin_amdgcn_cvt_pk_f32_fp8((int)pk, false);
    return make_float2(r[0], r[1]);
#else
    return make_float2(fp8_dec(pk & 0xFFu), fp8_dec((pk >> 8) & 0xFFu));
#endif
}
__device__ inline float2 fp8_hi2(uint pk) {
#if __has_builtin(__builtin_amdgcn_cvt_pk_f32_fp8)
    f32x2 r = __builtin_amdgcn_cvt_pk_f32_fp8((int)pk, true);
    return make_float2(r[0], r[1]);
#else
    return make_float2(fp8_dec((pk >> 16) & 0xFFu), fp8_dec(pk >> 24));
#endif
}

// ---------- prep: W^T bf16 (blocks 0..191) + gcur init (block 192) ----------
__global__ __launch_bounds__(256) void prep_kernel(const float* __restrict__ W1s,
                                                   const float* __restrict__ W1n,
                                                   const float* __restrict__ W2s,
                                                   const float* __restrict__ W2n,
                                                   ushort* __restrict__ wt,
                                                   int* __restrict__ gcur) {
    if (blockIdx.x == 192) {
        // one counter per 64B line; 196*16 = 3136 words, 256 threads cover via loop
        for (int i = threadIdx.x; i < NBKT * GCPAD; i += 256)
            gcur[i] = (i % GCPAD == 0) ? (i / GCPAD) * BSTRIDE : 0;
        return;
    }
    const int id = blockIdx.x * 256 + threadIdx.x;  // 0..49151
    const int m = id >> 14;
    const int r = id & 16383;
    const int c = r >> 7;
    const int k = r & 127;
    float v;
    if (m == 0) v = W1s[k * 128 + c];
    else if (m == 1) v = W1n[k * 128 + c];
    else v = (c < 64) ? W2s[k * 64 + c] : W2n[k * 64 + (c - 64)];
    wt[id] = bf16_rne(v);
}

// ---------- megaA: MFMA dual GEMM1 (even blocks) + edge binning (odd) ----------
__global__ __launch_bounds__(256) void megaA_kernel(
    const float* __restrict__ x, const ushort* __restrict__ wt,
    const float* __restrict__ b1, ushort* __restrict__ hbf,
    uchar* __restrict__ xnf8, const int* __restrict__ src,
    const int* __restrict__ dst, int* __restrict__ gcur,
    uint* __restrict__ pairbuf) {
    __shared__ uint4 sWq[2048];  // 32 KB: [128 cols][16 chunks of 8 bf16] swizzled
    const int bid = blockIdx.x;
    const int tid = threadIdx.x;

    if (bid & 1) {
        // ---------- bin branch: 2048 edges, rank-from-histogram ----------
        int* lhist = (int*)sWq;        // 256
        int* gbl = (int*)sWq + 256;    // 256
        const int t = bid >> 1;
        const int ebase = t * 2048;
        const int n = min(2048, NEDGES - ebase);
        const int nv4 = n >> 2;
        lhist[tid] = 0;
        __syncthreads();
        int4 sv[2], dv[2];
        int rk[2][4];
#pragma unroll
        for (int u = 0; u < 2; ++u) {
            const int i4 = tid + 256 * u;
            if (i4 < nv4) {
                sv[u] = ((const int4*)(src + ebase))[i4];
                dv[u] = ((const int4*)(dst + ebase))[i4];
                rk[u][0] = atomicAdd(&lhist[dv[u].x >> 9], 1);
                rk[u][1] = atomicAdd(&lhist[dv[u].y >> 9], 1);
                rk[u][2] = atomicAdd(&lhist[dv[u].z >> 9], 1);
                rk[u][3] = atomicAdd(&lhist[dv[u].w >> 9], 1);
            }
        }
        __syncthreads();
        const int cnt = lhist[tid];
        if (tid < NBKT && cnt > 0)
            gbl[tid] = atomicAdd(&gcur[tid * GCPAD], cnt);  // private 64B line
        __syncthreads();
#pragma unroll
        for (int u = 0; u < 2; ++u) {
            const int i4 = tid + 256 * u;
            if (i4 < nv4) {
                const int ss[4] = {sv[u].x, sv[u].y, sv[u].z, sv[u].w};
                const int dd[4] = {dv[u].x, dv[u].y, dv[u].z, dv[u].w};
#pragma unroll
                for (int j = 0; j < 4; ++j) {
                    const int b = dd[j] >> 9;
                    pairbuf[gbl[b] + rk[u][j]] =
                        ((uint)ss[j] << 9) | ((uint)dd[j] & 511u);
                }
            }
        }
        return;
    }

    // ---------- GEMM branch: 64 rows, W staged one matrix at a time ----------
    const int g = bid >> 1;  // 0..NGB-1
    const int w = tid >> 6;  // wave 0..3
    const int l = tid & 63;
    const int lg = l >> 4;
    const int lr = l & 15;
    const int rowbase = g * 64;
    const int arow = min(rowbase + w * 16 + lr, NNODES - 1);
    const float* xrow = x + (size_t)arow * 128;
    short8 ahi[4], alo[4];
#pragma unroll
    for (int ks = 0; ks < 4; ++ks) {
        const float4 va = *(const float4*)&xrow[ks * 32 + lg * 8];
        const float4 vb = *(const float4*)&xrow[ks * 32 + lg * 8 + 4];
        const float vv[8] = {va.x, va.y, va.z, va.w, vb.x, vb.y, vb.z, vb.w};
        short8 h8, l8;
#pragma unroll
        for (int j = 0; j < 8; ++j) {
            const ushort hu = bf16_rne(vv[j]);
            h8[j] = (short)hu;
            l8[j] = (short)bf16_rne(vv[j] - __uint_as_float((uint)hu << 16));
        }
        ahi[ks] = h8;
        alo[ks] = l8;
    }

#pragma unroll
    for (int wsel = 0; wsel < 2; ++wsel) {
        __syncthreads();  // protect previous wsel's reads
#pragma unroll
        for (int i = 0; i < 8; ++i) {
            const int cid = tid + 256 * i;  // 0..2047
            const int kc = cid & 15;
            const int c = cid >> 4;
            sWq[c * 16 + (kc ^ (c & 15))] =
                *(const uint4*)&wt[(size_t)(wsel * 2048 + cid) * 8];
        }
        __syncthreads();
#pragma unroll 4
        for (int ct = 0; ct < 8; ++ct) {
            f32x4 acc;
            if (wsel == 0) {
                const float bv = b1[ct * 16 + lr];
                acc = (f32x4){bv, bv, bv, bv};
            } else {
                acc = (f32x4){0.0f, 0.0f, 0.0f, 0.0f};
            }
            const int cbase = (ct * 16 + lr) * 16;
#pragma unroll
            for (int ks = 0; ks < 4; ++ks) {
                const short8 bf = *(const short8*)&sWq[cbase + ((4 * ks + lg) ^ lr)];
                acc = __builtin_amdgcn_mfma_f32_16x16x32_bf16(ahi[ks], bf, acc, 0, 0, 0);
                acc = __builtin_amdgcn_mfma_f32_16x16x32_bf16(alo[ks], bf, acc, 0, 0, 0);
            }
#pragma unroll
            for (int r_ = 0; r_ < 4; ++r_) {
                const int orow = rowbase + w * 16 + lg * 4 + r_;
                if (orow < NNODES) {
                    if (wsel == 0)
                        hbf[(size_t)orow * 128 + ct * 16 + lr] = bf16_rne(acc[r_]);
                    else
                        xnf8[(size_t)orow * 128 + ct * 16 + lr] = f32_to_fp8(acc[r_]);
                }
            }
        }
    }
}

// ---------- phase B: per-bucket CSR finalize (invd/rs/re/ebuf) ----------
__global__ __launch_bounds__(256) void bucket_kernel(const uint* __restrict__ pairbuf,
                                                     const int* __restrict__ gcur,
                                                     int* __restrict__ rs,
                                                     int* __restrict__ re,
                                                     float* __restrict__ invd,
                                                     int* __restrict__ ebuf) {
    __shared__ int ndeg[512];
    __shared__ int nofs[512];
    __shared__ int lcur[512];
    __shared__ int sps[256];
    const int b = blockIdx.x;
    const int tid = threadIdx.x;
    const int nb = b << 9;
    const int ln = min(512, NNODES - nb);
    const int base = b * BSTRIDE;
    const int cnt = gcur[b * GCPAD] - base;
    for (int i = tid; i < 512; i += 256) {
        ndeg[i] = 0;
        lcur[i] = 0;
    }
    __syncthreads();
    for (int i = tid; i < cnt; i += 256) {
        atomicAdd(&ndeg[pairbuf[base + i] & 511u], 1);
    }
    __syncthreads();
    for (int nidx = tid; nidx < ln; nidx += 256)
        invd[nb + nidx] = 1.0f / fmaxf((float)ndeg[nidx], 1.0f);
    const int a0 = ndeg[2 * tid];
    const int a1 = ndeg[2 * tid + 1];
    sps[tid] = a0 + a1;
    __syncthreads();
    for (int ofs = 1; ofs < 256; ofs <<= 1) {
        int t = (tid >= ofs) ? sps[tid - ofs] : 0;
        __syncthreads();
        sps[tid] += t;
        __syncthreads();
    }
    const int excl = sps[tid] - (a0 + a1);
    nofs[2 * tid] = excl;
    nofs[2 * tid + 1] = excl + a0;
    __syncthreads();
    for (int nidx = tid; nidx < ln; nidx += 256) {
        rs[nb + nidx] = base + nofs[nidx];
        re[nb + nidx] = base + nofs[nidx] + ndeg[nidx];
    }
    for (int i = tid; i < cnt; i += 256) {
        const uint e = pairbuf[base + i];
        const int nn = (int)(e & 511u);
        const int p = atomicAdd(&lcur[nn], 1);
        ebuf[base + nofs[nn] + p] = (int)(e >> 9);
    }
}

// ---------- layer-2 dual GEMM (MFMA): out = h@W2s + b2 (f32) ; hn fp8 ----------
__global__ __launch_bounds__(256) void gemm2_dual_kernel(
    const ushort* __restrict__ hbf, const ushort* __restrict__ wt2,
    const float* __restrict__ b2, float* __restrict__ out,
    uchar* __restrict__ hnf8) {
    __shared__ uint4 sWq[2048];  // 32 KB
    const int tid = threadIdx.x;
#pragma unroll
    for (int i = 0; i < 8; ++i) {
        const int cid = tid + 256 * i;
        const int kc = cid & 15;
        const int c = cid >> 4;
        sWq[c * 16 + (kc ^ (c & 15))] = *(const uint4*)&wt2[cid * 8];
    }
    const int w = tid >> 6;
    const int l = tid & 63;
    const int lg = l >> 4;
    const int lr = l & 15;
    const int rowbase = blockIdx.x * 64;
    const int arow = min(rowbase + w * 16 + lr, NNODES - 1);
    const ushort* hrow = hbf + (size_t)arow * 128;
    short8 a[4];
#pragma unroll
    for (int ks = 0; ks < 4; ++ks) a[ks] = *(const short8*)&hrow[ks * 32 + lg * 8];
    __syncthreads();

#pragma unroll 4
    for (int ct = 0; ct < 8; ++ct) {
        f32x4 acc;
        if (ct < 4) {
            const float bv = b2[ct * 16 + lr];
            acc = (f32x4){bv, bv, bv, bv};
        } else {
            acc = (f32x4){0.0f, 0.0f, 0.0f, 0.0f};
        }
        const int cbase = (ct * 16 + lr) * 16;
#pragma unroll
        for (int ks = 0; ks < 4; ++ks) {
            const short8 bf = *(const short8*)&sWq[cbase + ((4 * ks + lg) ^ lr)];
            acc = __builtin_amdgcn_mfma_f32_16x16x32_bf16(a[ks], bf, acc, 0, 0, 0);
        }
#pragma unroll
        for (int r_ = 0; r_ < 4; ++r_) {
            const int orow = rowbase + w * 16 + lg * 4 + r_;
            if (orow < NNODES) {
                if (ct < 4)
                    out[(size_t)orow * 64 + ct * 16 + lr] = acc[r_];
                else
                    hnf8[(size_t)orow * 64 + (ct - 4) * 16 + lr] = f32_to_fp8(acc[r_]);
            }
        }
    }
}

// ---------- layer-1 aggregation: fp8 gather, 32-lane group per node ----------
__global__ __launch_bounds__(256) void agg1_kernel(const int* __restrict__ rs,
                                                   const int* __restrict__ re,
                                                   const int* __restrict__ ebuf,
                                                   const float* __restrict__ invd,
                                                   const uchar* __restrict__ xnf8,
                                                   ushort* __restrict__ hbf) {
    const int node = blockIdx.x * 8 + (threadIdx.x >> 5);
    if (node >= NNODES) return;
    const int lane = threadIdx.x & 31;
    const int beg = rs[node];
    const int end = re[node];
    const uint* fp = (const uint*)xnf8 + lane;  // row stride 32 uints (128 B)
    float a0 = 0.0f, a1 = 0.0f, a2 = 0.0f, a3 = 0.0f;
    int i = beg;
    for (; i + 3 < end; i += 4) {
#pragma unroll
        for (int u = 0; u < 4; ++u) {
            const uint pk = fp[(size_t)ebuf[i + u] * 32];
            const float2 lo = fp8_lo2(pk);
            const float2 hi = fp8_hi2(pk);
            a0 += lo.x; a1 += lo.y; a2 += hi.x; a3 += hi.y;
        }
    }
    for (; i < end; ++i) {
        const uint pk = fp[(size_t)ebuf[i] * 32];
        const float2 lo = fp8_lo2(pk);
        const float2 hi = fp8_hi2(pk);
        a0 += lo.x; a1 += lo.y; a2 += hi.x; a3 += hi.y;
    }
    const float w = invd[node];
    uint* hp = (uint*)hbf + (size_t)node * 64 + lane * 2;
    uint2 hv = *(uint2*)hp;
    float2 h0 = unpack_bf2(hv.x);
    float2 h1 = unpack_bf2(hv.y);
    h0.x = fmaxf(fmaf(w, a0, h0.x), 0.0f);
    h0.y = fmaxf(fmaf(w, a1, h0.y), 0.0f);
    h1.x = fmaxf(fmaf(w, a2, h1.x), 0.0f);
    h1.y = fmaxf(fmaf(w, a3, h1.y), 0.0f);
    hv.x = pack_bf2(h0.x, h0.y);
    hv.y = pack_bf2(h1.x, h1.y);
    *(uint2*)hp = hv;
}

// ---------- layer-2 aggregation: fp8 gather, 32-lane group per node ----------
__global__ __launch_bounds__(256) void agg2_kernel(const int* __restrict__ rs,
                                                   const int* __restrict__ re,
                                                   const int* __restrict__ ebuf,
                                                   const float* __restrict__ invd,
                                                   const uchar* __restrict__ hnf8,
                                                   float* __restrict__ out) {
    const int node = blockIdx.x * 8 + (threadIdx.x >> 5);
    if (node >= NNODES) return;
    const int lane = threadIdx.x & 31;
    const int beg = rs[node];
    const int end = re[node];
    const ushort* fp = (const ushort*)hnf8 + lane;  // row stride 32 ushorts (64 B)
    float a0 = 0.0f, a1 = 0.0f;
    int i = beg;
    for (; i + 3 < end; i += 4) {
#pragma unroll
        for (int u = 0; u < 4; ++u) {
            const uint pk = (uint)fp[(size_t)ebuf[i + u] * 32];
            const float2 v = fp8_lo2(pk);
            a0 += v.x; a1 += v.y;
        }
    }
    for (; i < end; ++i) {
        const uint pk = (uint)fp[(size_t)ebuf[i] * 32];
        const float2 v = fp8_lo2(pk);
        a0 += v.x; a1 += v.y;
    }
    const float w = invd[node];
    float2* op = (float2*)&out[(size_t)node * 64 + lane * 2];
    float2 ov = *op;
    ov.x = fmaf(w, a0, ov.x);
    ov.y = fmaf(w, a1, ov.y);
    *op = ov;
}

extern "C" void kernel_launch(void* const* d_in, const int* in_sizes, int n_in,
                              void* d_out, int out_size, void* d_ws, size_t ws_size,
                              hipStream_t stream) {
    const float* x   = (const float*)d_in[0];
    const int*   ei  = (const int*)d_in[1];
    const float* W1s = (const float*)d_in[2];
    const float* W1n = (const float*)d_in[3];
    const float* b1  = (const float*)d_in[4];
    const float* W2s = (const float*)d_in[5];
    const float* W2n = (const float*)d_in[6];
    const float* b2  = (const float*)d_in[7];
    float* out = (float*)d_out;

    const int* src = ei;           // edge_index row 0
    const int* dst = ei + NEDGES;  // edge_index row 1

    // workspace carve-up (word offsets); ebuf/pairbuf sized NBKT*BSTRIDE
    int* w = (int*)d_ws;
    int*    gcur    = w;                        // 3,136 (196 x 16-word lines) -> pad 3,200
    int*    rs      = w + 3200;                 // 100,000
    int*    re      = w + 103200;               // 100,000
    float*  invd    = (float*)(w + 203200);     // 100,000
    int*    ebuf    = w + 303200;               // 3,612,672
    uint*   pairbuf = (uint*)(w + 3915872);     // 3,612,672
    uchar*  xnf8    = (uchar*)(w + 7528544);    // N*128 fp8 (3.2M words)
    ushort* hbf     = (ushort*)(w + 10728544);  // N*128 bf16 (6.4M words)
    ushort* wtbuf   = (ushort*)(w + 17128544);  // 49,152 ushorts
    uchar*  hnf8    = xnf8;  // reuse after agg1 (needs N*64 fp8)

    prep_kernel<<<193, 256, 0, stream>>>(W1s, W1n, W2s, W2n, wtbuf, gcur);

    // layer-1 dual MFMA GEMM fused 1:1 with edge binning
    megaA_kernel<<<2 * NTILES2, 256, 0, stream>>>(x, wtbuf, b1, hbf, xnf8, src, dst,
                                                  gcur, pairbuf);
    bucket_kernel<<<NBKT, 256, 0, stream>>>(pairbuf, gcur, rs, re, invd, ebuf);

    agg1_kernel<<<NNODES / 8, 256, 0, stream>>>(rs, re, ebuf, invd, xnf8, hbf);

    gemm2_dual_kernel<<<NGB, 256, 0, stream>>>(hbf, wtbuf + 32768, b2, out, hnf8);
    agg2_kernel<<<NNODES / 8, 256, 0, stream>>>(rs, re, ebuf, invd, hnf8, out);
}

// Round 18
// 245.695 us; speedup vs baseline: 1.0164x; 1.0164x over previous
//
#include <hip/hip_runtime.h>

#define NNODES 100000
#define NEDGES 3200000
#define NBKT 196        // buckets of 512 nodes (dst>>9)
#define NTILES2 1563    // bin tiles of 2048 edges
#define NGB 1563        // ceil(NNODES/64) GEMM blocks (64 rows)
#define BSTRIDE 18432   // fixed pairbuf/ebuf stride per bucket (mean 16327 + 16 sigma)
#define GCPAD 16        // gcur stride in words: one 64B cache line per bucket

typedef unsigned int uint;
typedef unsigned short ushort;
typedef unsigned char uchar;
typedef __attribute__((ext_vector_type(8))) short short8;   // 8 bf16 (4 VGPRs)
typedef __attribute__((ext_vector_type(4))) float f32x4;
typedef __attribute__((ext_vector_type(2))) float f32x2;

__device__ inline ushort bf16_rne(float f) {
    uint u = __float_as_uint(f);
    return (ushort)((u + 0x7FFFu + ((u >> 16) & 1u)) >> 16);
}
__device__ inline uint pack_bf2(float a, float b) {
    return (uint)bf16_rne(a) | ((uint)bf16_rne(b) << 16);
}
__device__ inline float2 unpack_bf2(uint v) {
    float2 r;
    r.x = __uint_as_float(v << 16);
    r.y = __uint_as_float(v & 0xFFFF0000u);
    return r;
}

// ---- fp8 e4m3fn (OCP) encode/decode; encoder flushes |v|<2^-6 to 0 ----
__device__ inline uchar f32_to_fp8(float f) {
    uint u = __float_as_uint(f);
    uint s = (u >> 24) & 0x80u;
    uint e = (u >> 23) & 0xFFu;
    if (e < 121u) return (uchar)s;  // flush to signed zero
    uint m = u & 0x7FFFFFu;
    uint r = (m + 0x7FFFFu + ((m >> 20) & 1u)) >> 20;  // RNE to 3 bits
    uint em = ((e - 120u) << 3) + r;                   // carry folds into exp
    return (uchar)(s | em);
}
__device__ inline float fp8_dec(uint b) {
    uint s = (b & 0x80u) << 24;
    uint em = b & 0x7Fu;
    float v = __uint_as_float(s | ((em + 960u) << 20));
    return em ? v : 0.0f;
}
__device__ inline float2 fp8_lo2(uint pk) {
#if __has_builtin(__builtin_amdgcn_cvt_pk_f32_fp8)
    f32x2 r = __builtin_amdgcn_cvt_pk_f32_fp8((int)pk, false);
    return make_float2(r[0], r[1]);
#else
    return make_float2(fp8_dec(pk & 0xFFu), fp8_dec((pk >> 8) & 0xFFu));
#endif
}
__device__ inline float2 fp8_hi2(uint pk) {
#if __has_builtin(__builtin_amdgcn_cvt_pk_f32_fp8)
    f32x2 r = __builtin_amdgcn_cvt_pk_f32_fp8((int)pk, true);
    return make_float2(r[0], r[1]);
#else
    return make_float2(fp8_dec((pk >> 16) & 0xFFu), fp8_dec(pk >> 24));
#endif
}

// ---------- prep: W^T bf16 (blocks 0..191) + gcur init (block 192) ----------
__global__ __launch_bounds__(256) void prep_kernel(const float* __restrict__ W1s,
                                                   const float* __restrict__ W1n,
                                                   const float* __restrict__ W2s,
                                                   const float* __restrict__ W2n,
                                                   ushort* __restrict__ wt,
                                                   int* __restrict__ gcur) {
    if (blockIdx.x == 192) {
        for (int i = threadIdx.x; i < NBKT * GCPAD; i += 256)
            gcur[i] = (i % GCPAD == 0) ? (i / GCPAD) * BSTRIDE : 0;
        return;
    }
    const int id = blockIdx.x * 256 + threadIdx.x;  // 0..49151
    const int m = id >> 14;
    const int r = id & 16383;
    const int c = r >> 7;
    const int k = r & 127;
    float v;
    if (m == 0) v = W1s[k * 128 + c];
    else if (m == 1) v = W1n[k * 128 + c];
    else v = (c < 64) ? W2s[k * 64 + c] : W2n[k * 64 + (c - 64)];
    wt[id] = bf16_rne(v);
}

// ---------- megaA: MFMA dual GEMM1 (even blocks) + edge binning (odd) ----------
__global__ __launch_bounds__(256) void megaA_kernel(
    const float* __restrict__ x, const ushort* __restrict__ wt,
    const float* __restrict__ b1, ushort* __restrict__ hbf,
    uchar* __restrict__ xnf8, const int* __restrict__ src,
    const int* __restrict__ dst, int* __restrict__ gcur,
    uint* __restrict__ pairbuf) {
    __shared__ uint4 sWq[2048];  // 32 KB: [128 cols][16 chunks of 8 bf16] swizzled
    const int bid = blockIdx.x;
    const int tid = threadIdx.x;

    if (bid & 1) {
        // ---------- bin branch: 2048 edges, rank-from-histogram ----------
        int* lhist = (int*)sWq;        // 256
        int* gbl = (int*)sWq + 256;    // 256
        const int t = bid >> 1;
        const int ebase = t * 2048;
        const int n = min(2048, NEDGES - ebase);
        const int nv4 = n >> 2;
        lhist[tid] = 0;
        __syncthreads();
        int4 sv[2], dv[2];
        int rk[2][4];
#pragma unroll
        for (int u = 0; u < 2; ++u) {
            const int i4 = tid + 256 * u;
            if (i4 < nv4) {
                sv[u] = ((const int4*)(src + ebase))[i4];
                dv[u] = ((const int4*)(dst + ebase))[i4];
                rk[u][0] = atomicAdd(&lhist[dv[u].x >> 9], 1);
                rk[u][1] = atomicAdd(&lhist[dv[u].y >> 9], 1);
                rk[u][2] = atomicAdd(&lhist[dv[u].z >> 9], 1);
                rk[u][3] = atomicAdd(&lhist[dv[u].w >> 9], 1);
            }
        }
        __syncthreads();
        const int cnt = lhist[tid];
        if (tid < NBKT && cnt > 0)
            gbl[tid] = atomicAdd(&gcur[tid * GCPAD], cnt);
        __syncthreads();
#pragma unroll
        for (int u = 0; u < 2; ++u) {
            const int i4 = tid + 256 * u;
            if (i4 < nv4) {
                const int ss[4] = {sv[u].x, sv[u].y, sv[u].z, sv[u].w};
                const int dd[4] = {dv[u].x, dv[u].y, dv[u].z, dv[u].w};
#pragma unroll
                for (int j = 0; j < 4; ++j) {
                    const int b = dd[j] >> 9;
                    pairbuf[gbl[b] + rk[u][j]] =
                        ((uint)ss[j] << 9) | ((uint)dd[j] & 511u);
                }
            }
        }
        return;
    }

    // ---------- GEMM branch: 64 rows, W staged one matrix at a time ----------
    const int g = bid >> 1;  // 0..NGB-1
    const int w = tid >> 6;  // wave 0..3
    const int l = tid & 63;
    const int lg = l >> 4;
    const int lr = l & 15;
    const int rowbase = g * 64;
    const int arow = min(rowbase + w * 16 + lr, NNODES - 1);
    const float* xrow = x + (size_t)arow * 128;
    short8 ahi[4], alo[4];
#pragma unroll
    for (int ks = 0; ks < 4; ++ks) {
        const float4 va = *(const float4*)&xrow[ks * 32 + lg * 8];
        const float4 vb = *(const float4*)&xrow[ks * 32 + lg * 8 + 4];
        const float vv[8] = {va.x, va.y, va.z, va.w, vb.x, vb.y, vb.z, vb.w};
        short8 h8, l8;
#pragma unroll
        for (int j = 0; j < 8; ++j) {
            const ushort hu = bf16_rne(vv[j]);
            h8[j] = (short)hu;
            l8[j] = (short)bf16_rne(vv[j] - __uint_as_float((uint)hu << 16));
        }
        ahi[ks] = h8;
        alo[ks] = l8;
    }

#pragma unroll
    for (int wsel = 0; wsel < 2; ++wsel) {
        __syncthreads();  // protect previous wsel's reads
#pragma unroll
        for (int i = 0; i < 8; ++i) {
            const int cid = tid + 256 * i;  // 0..2047
            const int kc = cid & 15;
            const int c = cid >> 4;
            sWq[c * 16 + (kc ^ (c & 15))] =
                *(const uint4*)&wt[(size_t)(wsel * 2048 + cid) * 8];
        }
        __syncthreads();
#pragma unroll 4
        for (int ct = 0; ct < 8; ++ct) {
            f32x4 acc;
            if (wsel == 0) {
                const float bv = b1[ct * 16 + lr];
                acc = (f32x4){bv, bv, bv, bv};
            } else {
                acc = (f32x4){0.0f, 0.0f, 0.0f, 0.0f};
            }
            const int cbase = (ct * 16 + lr) * 16;
#pragma unroll
            for (int ks = 0; ks < 4; ++ks) {
                const short8 bf = *(const short8*)&sWq[cbase + ((4 * ks + lg) ^ lr)];
                acc = __builtin_amdgcn_mfma_f32_16x16x32_bf16(ahi[ks], bf, acc, 0, 0, 0);
                acc = __builtin_amdgcn_mfma_f32_16x16x32_bf16(alo[ks], bf, acc, 0, 0, 0);
            }
#pragma unroll
            for (int r_ = 0; r_ < 4; ++r_) {
                const int orow = rowbase + w * 16 + lg * 4 + r_;
                if (orow < NNODES) {
                    if (wsel == 0)
                        hbf[(size_t)orow * 128 + ct * 16 + lr] = bf16_rne(acc[r_]);
                    else
                        xnf8[(size_t)orow * 128 + ct * 16 + lr] = f32_to_fp8(acc[r_]);
                }
            }
        }
    }
}

// ---------- phase B: per-bucket CSR finalize (invd/rs/re/ebuf) ----------
__global__ __launch_bounds__(256) void bucket_kernel(const uint* __restrict__ pairbuf,
                                                     const int* __restrict__ gcur,
                                                     int* __restrict__ rs,
                                                     int* __restrict__ re,
                                                     float* __restrict__ invd,
                                                     int* __restrict__ ebuf) {
    __shared__ int ndeg[512];
    __shared__ int nofs[512];
    __shared__ int lcur[512];
    __shared__ int sps[256];
    const int b = blockIdx.x;
    const int tid = threadIdx.x;
    const int nb = b << 9;
    const int ln = min(512, NNODES - nb);
    const int base = b * BSTRIDE;
    const int cnt = gcur[b * GCPAD] - base;
    for (int i = tid; i < 512; i += 256) {
        ndeg[i] = 0;
        lcur[i] = 0;
    }
    __syncthreads();
    for (int i = tid; i < cnt; i += 256) {
        atomicAdd(&ndeg[pairbuf[base + i] & 511u], 1);
    }
    __syncthreads();
    for (int nidx = tid; nidx < ln; nidx += 256)
        invd[nb + nidx] = 1.0f / fmaxf((float)ndeg[nidx], 1.0f);
    const int a0 = ndeg[2 * tid];
    const int a1 = ndeg[2 * tid + 1];
    sps[tid] = a0 + a1;
    __syncthreads();
    for (int ofs = 1; ofs < 256; ofs <<= 1) {
        int t = (tid >= ofs) ? sps[tid - ofs] : 0;
        __syncthreads();
        sps[tid] += t;
        __syncthreads();
    }
    const int excl = sps[tid] - (a0 + a1);
    nofs[2 * tid] = excl;
    nofs[2 * tid + 1] = excl + a0;
    __syncthreads();
    for (int nidx = tid; nidx < ln; nidx += 256) {
        rs[nb + nidx] = base + nofs[nidx];
        re[nb + nidx] = base + nofs[nidx] + ndeg[nidx];
    }
    for (int i = tid; i < cnt; i += 256) {
        const uint e = pairbuf[base + i];
        const int nn = (int)(e & 511u);
        const int p = atomicAdd(&lcur[nn], 1);
        ebuf[base + nofs[nn] + p] = (int)(e >> 9);
    }
}

// ---------- layer-2 dual GEMM (MFMA): out = h@W2s + b2 (f32) ; hn fp8 ----------
__global__ __launch_bounds__(256) void gemm2_dual_kernel(
    const ushort* __restrict__ hbf, const ushort* __restrict__ wt2,
    const float* __restrict__ b2, float* __restrict__ out,
    uchar* __restrict__ hnf8) {
    __shared__ uint4 sWq[2048];  // 32 KB
    const int tid = threadIdx.x;
#pragma unroll
    for (int i = 0; i < 8; ++i) {
        const int cid = tid + 256 * i;
        const int kc = cid & 15;
        const int c = cid >> 4;
        sWq[c * 16 + (kc ^ (c & 15))] = *(const uint4*)&wt2[cid * 8];
    }
    const int w = tid >> 6;
    const int l = tid & 63;
    const int lg = l >> 4;
    const int lr = l & 15;
    const int rowbase = blockIdx.x * 64;
    const int arow = min(rowbase + w * 16 + lr, NNODES - 1);
    const ushort* hrow = hbf + (size_t)arow * 128;
    short8 a[4];
#pragma unroll
    for (int ks = 0; ks < 4; ++ks) a[ks] = *(const short8*)&hrow[ks * 32 + lg * 8];
    __syncthreads();

#pragma unroll 4
    for (int ct = 0; ct < 8; ++ct) {
        f32x4 acc;
        if (ct < 4) {
            const float bv = b2[ct * 16 + lr];
            acc = (f32x4){bv, bv, bv, bv};
        } else {
            acc = (f32x4){0.0f, 0.0f, 0.0f, 0.0f};
        }
        const int cbase = (ct * 16 + lr) * 16;
#pragma unroll
        for (int ks = 0; ks < 4; ++ks) {
            const short8 bf = *(const short8*)&sWq[cbase + ((4 * ks + lg) ^ lr)];
            acc = __builtin_amdgcn_mfma_f32_16x16x32_bf16(a[ks], bf, acc, 0, 0, 0);
        }
#pragma unroll
        for (int r_ = 0; r_ < 4; ++r_) {
            const int orow = rowbase + w * 16 + lg * 4 + r_;
            if (orow < NNODES) {
                if (ct < 4)
                    out[(size_t)orow * 64 + ct * 16 + lr] = acc[r_];
                else
                    hnf8[(size_t)orow * 64 + (ct - 4) * 16 + lr] = f32_to_fp8(acc[r_]);
            }
        }
    }
}

// ---------- layer-1 aggregation: fp8 gather, 32-lane group per node ----------
__global__ __launch_bounds__(256) void agg1_kernel(const int* __restrict__ rs,
                                                   const int* __restrict__ re,
                                                   const int* __restrict__ ebuf,
                                                   const float* __restrict__ invd,
                                                   const uchar* __restrict__ xnf8,
                                                   ushort* __restrict__ hbf) {
    const int node = blockIdx.x * 8 + (threadIdx.x >> 5);
    if (node >= NNODES) return;
    const int lane = threadIdx.x & 31;
    const int beg = rs[node];
    const int end = re[node];
    const uint* fp = (const uint*)xnf8 + lane;  // row stride 32 uints (128 B)
    float a0 = 0.0f, a1 = 0.0f, a2 = 0.0f, a3 = 0.0f;
    int i = beg;
    for (; i + 3 < end; i += 4) {
#pragma unroll
        for (int u = 0; u < 4; ++u) {
            const uint pk = fp[(size_t)ebuf[i + u] * 32];
            const float2 lo = fp8_lo2(pk);
            const float2 hi = fp8_hi2(pk);
            a0 += lo.x; a1 += lo.y; a2 += hi.x; a3 += hi.y;
        }
    }
    for (; i < end; ++i) {
        const uint pk = fp[(size_t)ebuf[i] * 32];
        const float2 lo = fp8_lo2(pk);
        const float2 hi = fp8_hi2(pk);
        a0 += lo.x; a1 += lo.y; a2 += hi.x; a3 += hi.y;
    }
    const float w = invd[node];
    uint* hp = (uint*)hbf + (size_t)node * 64 + lane * 2;
    uint2 hv = *(uint2*)hp;
    float2 h0 = unpack_bf2(hv.x);
    float2 h1 = unpack_bf2(hv.y);
    h0.x = fmaxf(fmaf(w, a0, h0.x), 0.0f);
    h0.y = fmaxf(fmaf(w, a1, h0.y), 0.0f);
    h1.x = fmaxf(fmaf(w, a2, h1.x), 0.0f);
    h1.y = fmaxf(fmaf(w, a3, h1.y), 0.0f);
    hv.x = pack_bf2(h0.x, h0.y);
    hv.y = pack_bf2(h1.x, h1.y);
    *(uint2*)hp = hv;
}

// ---------- layer-2 aggregation: uint gather, 2 edge-slots x 16 cols per node ----
__global__ __launch_bounds__(256) void agg2_kernel(const int* __restrict__ rs,
                                                   const int* __restrict__ re,
                                                   const int* __restrict__ ebuf,
                                                   const float* __restrict__ invd,
                                                   const uchar* __restrict__ hnf8,
                                                   float* __restrict__ out) {
    const int node = blockIdx.x * 8 + (threadIdx.x >> 5);
    if (node >= NNODES) return;
    const int lane = threadIdx.x & 31;
    const int e2 = lane >> 4;    // edge parity slot 0/1
    const int c = lane & 15;     // uint column (4 fp8 = 4 cols)
    const int beg = rs[node];
    const int end = re[node];
    const uint* fp = (const uint*)hnf8 + c;  // row stride 16 uints (64 B)
    float a0 = 0.0f, a1 = 0.0f, a2 = 0.0f, a3 = 0.0f;
    int i = beg + e2;
    for (; i + 2 < end; i += 4) {
        const uint pka = fp[(size_t)ebuf[i] * 16];
        const uint pkb = fp[(size_t)ebuf[i + 2] * 16];
        const float2 la = fp8_lo2(pka);
        const float2 ha = fp8_hi2(pka);
        const float2 lb = fp8_lo2(pkb);
        const float2 hb = fp8_hi2(pkb);
        a0 += la.x + lb.x; a1 += la.y + lb.y;
        a2 += ha.x + hb.x; a3 += ha.y + hb.y;
    }
    if (i < end) {
        const uint pk = fp[(size_t)ebuf[i] * 16];
        const float2 lo = fp8_lo2(pk);
        const float2 hi = fp8_hi2(pk);
        a0 += lo.x; a1 += lo.y; a2 += hi.x; a3 += hi.y;
    }
    // combine the two edge-parity slots (lanes l and l^16 hold same columns)
    a0 += __shfl_xor(a0, 16);
    a1 += __shfl_xor(a1, 16);
    a2 += __shfl_xor(a2, 16);
    a3 += __shfl_xor(a3, 16);
    if (e2 == 0) {
        const float w = invd[node];
        float4* op = (float4*)&out[(size_t)node * 64 + c * 4];
        float4 ov = *op;
        ov.x = fmaf(w, a0, ov.x);
        ov.y = fmaf(w, a1, ov.y);
        ov.z = fmaf(w, a2, ov.z);
        ov.w = fmaf(w, a3, ov.w);
        *op = ov;
    }
}

extern "C" void kernel_launch(void* const* d_in, const int* in_sizes, int n_in,
                              void* d_out, int out_size, void* d_ws, size_t ws_size,
                              hipStream_t stream) {
    const float* x   = (const float*)d_in[0];
    const int*   ei  = (const int*)d_in[1];
    const float* W1s = (const float*)d_in[2];
    const float* W1n = (const float*)d_in[3];
    const float* b1  = (const float*)d_in[4];
    const float* W2s = (const float*)d_in[5];
    const float* W2n = (const float*)d_in[6];
    const float* b2  = (const float*)d_in[7];
    float* out = (float*)d_out;

    const int* src = ei;           // edge_index row 0
    const int* dst = ei + NEDGES;  // edge_index row 1

    // workspace carve-up (word offsets); ebuf/pairbuf sized NBKT*BSTRIDE
    int* w = (int*)d_ws;
    int*    gcur    = w;                        // 3,136 (196 x 16-word lines) -> pad 3,200
    int*    rs      = w + 3200;                 // 100,000
    int*    re      = w + 103200;               // 100,000
    float*  invd    = (float*)(w + 203200);     // 100,000
    int*    ebuf    = w + 303200;               // 3,612,672
    uint*   pairbuf = (uint*)(w + 3915872);     // 3,612,672
    uchar*  xnf8    = (uchar*)(w + 7528544);    // N*128 fp8 (3.2M words)
    ushort* hbf     = (ushort*)(w + 10728544);  // N*128 bf16 (6.4M words)
    ushort* wtbuf   = (ushort*)(w + 17128544);  // 49,152 ushorts
    uchar*  hnf8    = xnf8;  // reuse after agg1 (needs N*64 fp8)

    prep_kernel<<<193, 256, 0, stream>>>(W1s, W1n, W2s, W2n, wtbuf, gcur);

    // layer-1 dual MFMA GEMM fused 1:1 with edge binning
    megaA_kernel<<<2 * NTILES2, 256, 0, stream>>>(x, wtbuf, b1, hbf, xnf8, src, dst,
                                                  gcur, pairbuf);
    bucket_kernel<<<NBKT, 256, 0, stream>>>(pairbuf, gcur, rs, re, invd, ebuf);

    agg1_kernel<<<NNODES / 8, 256, 0, stream>>>(rs, re, ebuf, invd, xnf8, hbf);

    gemm2_dual_kernel<<<NGB, 256, 0, stream>>>(hbf, wtbuf + 32768, b2, out, hnf8);
    agg2_kernel<<<NNODES / 8, 256, 0, stream>>>(rs, re, ebuf, invd, hnf8, out);
}